// Round 15
// baseline (20.818 us; speedup 1.0000x reference)
//
#include <hip/hip_runtime.h>

// YOLO-style multi-level detection loss — gridless, gather-parallel, 8-deep MLP.
// Input dict order (setup_inputs interleaves!):
//   d_in[0]=cls0 d_in[1]=box0 d_in[2]=obj0
//   d_in[3]=cls1 d_in[4]=box1 d_in[5]=obj1
//   d_in[6]=cls2 d_in[7]=box2 d_in[8]=obj2
//   d_in[9]=boxes [B,N,4]  d_in[10]=labels [B,N]
// Output: 4 floats: total, loss_cls, loss_box, loss_obj
//
// bce(x,t) = bce(x,0) - x*t for t in {0,1}:
//   loss_obj*cnt = sum_all bce0(obj) + sum_winners(-obj)
//   cls/box only need predictions AT positive cells.
// Ladder: 210us (latency) -> 78 (occupancy) -> 50 (fast exp/log) -> 35 (no
// memset) -> 27 (1 thread/load) -> 25 (issue-early) -> 23.5 (2-deep) ->
// 20.7 (4-deep). Now 8-deep: one G-block per (level,batch); each 32-lane
// group owns 8 boxes, 8 scattered loads in flight per thread before the
// shared shfl-OR scan. NG 768->384.
// Winner/mask: batch's 64 cells in LDS; lane c probes boxes c and c+32 per
// entry; bit31 = "later box shares my cell" (last box wins = JAX sequential
// scatter-set); bits 0..19 = label mask. Lane c<20 = cls channel c, 20..23 =
// box channel, 24 = obj. No atomics, no ws clearing (poison-proof).

#define NCLS  20
#define BATCH 128
#define TPB   256
// cells per level (BATCH * H * W)
#define C0 819200
#define C1 204800
#define C2 51200
// G-blocks: 64 entries/block (8 groups x 8) = one batch; 128/level
#define NG_PER_LVL 128
#define NG  (3 * NG_PER_LVL)    // 384
// A-blocks: stream bce0(obj); one float4 per thread (exact partitions)
#define NA0 800
#define NA1 200
#define NA2 50
#define NA  (NA0 + NA1 + NA2)   // 1050
#define NBLK (NG + NA)          // 1434

struct AllPtrs {
    const float *cls0, *box0, *obj0;
    const float *cls1, *box1, *obj1;
    const float *cls2, *box2, *obj2;
};

__device__ __forceinline__ float bce0(float x) {
    // bce_with_logits(x,0) = max(x,0) + log1p(exp(-|x|)); v_exp/v_log fast
    // form (log(1+e)==log1p(e) to fp32 for e in (2^-24,1]; abs err <=6e-8).
    return fmaxf(x, 0.0f) + __logf(1.0f + __expf(-fabsf(x)));
}

__device__ __forceinline__ float wave_sum(float v) {
    #pragma unroll
    for (int o = 32; o > 0; o >>= 1) v += __shfl_down(v, o);
    return v;
}

__global__ void __launch_bounds__(TPB)
fused_loss(AllPtrs p, const float4* __restrict__ boxes, const int* __restrict__ labels,
           float* __restrict__ Aout, float4* __restrict__ Gout) {
    __shared__ float  shA[4];
    __shared__ int    s_cell[64];
    __shared__ int    s_lab[64];
    __shared__ float  s_cx[64], s_cy[64], s_w[64], s_h[64];
    __shared__ float4 shG[8];

    int blk = blockIdx.x;
    if (blk >= NG) {
        // ---- A path: sum bce0(obj) over all cells of one level slice ----
        int a = blk - NG;
        const float* obj;
        int i;
        if (a < NA0)            { obj = p.obj0; i = a * TPB + threadIdx.x; }
        else if (a < NA0 + NA1) { obj = p.obj1; i = (a - NA0) * TPB + threadIdx.x; }
        else                    { obj = p.obj2; i = (a - NA0 - NA1) * TPB + threadIdx.x; }
        float4 v = ((const float4*)obj)[i];
        float s = bce0(v.x) + bce0(v.y) + bce0(v.z) + bce0(v.w);
        s = wave_sum(s);
        int wid = threadIdx.x >> 6, lane = threadIdx.x & 63;
        if (lane == 0) shA[wid] = s;
        __syncthreads();
        if (threadIdx.x == 0)
            Aout[a] = shA[0] + shA[1] + shA[2] + shA[3];
        return;
    }

    // ---- G path: one block per (level,batch); 32-lane group = 8 entries ----
    int gi  = blk;                    // 0..383
    int l   = (gi >= 2 * NG_PER_LVL) ? 2 : (gi >= NG_PER_LVL ? 1 : 0);
    int batch = gi - l * NG_PER_LVL;  // 0..127

    const float is[3]  = {0.125f, 0.0625f, 0.03125f};
    const int   Ws[3]  = {80, 40, 20};
    const int   HWs[3] = {6400, 1600, 400};
    const float* clsP[3] = {p.cls0, p.cls1, p.cls2};
    const float* boxP[3] = {p.box0, p.box1, p.box2};
    const float* objP[3] = {p.obj0, p.obj1, p.obj2};
    const float isl = is[l];
    const int   Wl  = Ws[l];
    const int   HW  = HWs[l];

    int t = threadIdx.x;
    if (t < 64) {                    // stage batch geometry in LDS
        float4 bx = boxes[batch * 64 + t];
        float cx = (bx.x + bx.z) * 0.5f, cy = (bx.y + bx.w) * 0.5f;
        s_cx[t] = cx; s_cy[t] = cy;
        s_w[t]  = bx.z - bx.x; s_h[t] = bx.w - bx.y;
        s_lab[t] = labels[batch * 64 + t];
        int gx = (int)floorf(cx * isl);
        int gy = (int)floorf(cy * isl);
        bool valid = (gx >= 0) & (gy >= 0) & (gx < Wl) & (gy < Wl);
        s_cell[t] = valid ? gy * Wl + gx : -1;
    }
    __syncthreads();

    int g = t >> 5;                  // group 0..7; entry e -> box n = g + 8e
    int c = t & 31;                  // channel lane
    int cell[8], lc[8];
    #pragma unroll
    for (int e = 0; e < 8; ++e) {
        cell[e] = s_cell[g + 8 * e];
        lc[e]   = (cell[e] >= 0) ? cell[e] : 0;
    }

    // ---- ISSUE all 8 scattered loads EARLY (latency overlaps scan) ----
    float ld[8] = {0.f, 0.f, 0.f, 0.f, 0.f, 0.f, 0.f, 0.f};
    if (c < NCLS) {
        const float* cb = clsP[l] + (size_t)(batch * NCLS + c) * HW;
        #pragma unroll
        for (int e = 0; e < 8; ++e) ld[e] = cb[lc[e]];
    } else if (c < 24) {
        const float* bb = boxP[l] + (size_t)(batch * 4 + (c - 20)) * HW;
        #pragma unroll
        for (int e = 0; e < 8; ++e) ld[e] = bb[lc[e]];
    } else if (c == 24) {
        const float* ob = objP[l] + (size_t)batch * HW;
        #pragma unroll
        for (int e = 0; e < 8; ++e) ld[e] = ob[lc[e]];
    }

    // box-target values for lanes 20..23 (independent of loads)
    float tv[8] = {0.f, 0.f, 0.f, 0.f, 0.f, 0.f, 0.f, 0.f};
    if (c >= 20 && c < 24) {
        int k = c - 20;
        #pragma unroll
        for (int e = 0; e < 8; ++e) {
            int nn = g + 8 * e;
            if (k == 0)      { float sx = s_cx[nn] * isl; tv[e] = sx - floorf(sx); }
            else if (k == 1) { float sy = s_cy[nn] * isl; tv[e] = sy - floorf(sy); }
            else if (k == 2) { tv[e] = __logf(s_w[nn] * isl + 1e-6f); }
            else             { tv[e] = __logf(s_h[nn] * isl + 1e-6f); }
        }
    }

    // ---- winner + label-mask scan for all 8 entries (overlaps loads) ----
    int cj0 = s_cell[c], cj1 = s_cell[c + 32];
    unsigned lb0 = 1u << s_lab[c], lb1 = 1u << s_lab[c + 32];
    unsigned comb[8];
    #pragma unroll
    for (int e = 0; e < 8; ++e) {
        int nn = g + 8 * e;
        unsigned cm = 0u;            // bits0..19 mask, bit31 violation
        if (cell[e] >= 0) {
            if (cj0 == cell[e]) cm |= lb0 | ((c > nn)      ? 0x80000000u : 0u);
            if (cj1 == cell[e]) cm |= lb1 | ((c + 32 > nn) ? 0x80000000u : 0u);
        }
        comb[e] = cm;
    }
    #pragma unroll
    for (int o = 16; o > 0; o >>= 1) {
        #pragma unroll
        for (int e = 0; e < 8; ++e)
            comb[e] |= (unsigned)__shfl_xor((int)comb[e], o, 32);
    }

    // ---- apply win/mask to loaded values ----
    float v_cls = 0.f, v_box = 0.f, v_obj = 0.f, v_np = 0.f;
    #pragma unroll
    for (int e = 0; e < 8; ++e) {
        bool win = (cell[e] >= 0) && !(comb[e] >> 31);
        unsigned mask = comb[e] & 0xFFFFFu;
        if (win) {
            if (c == 0) v_np += 1.f;     // group win count on lane 0 only
            if (c < NCLS) {
                v_cls += bce0(ld[e]) - (((mask >> c) & 1u) ? ld[e] : 0.f);
            } else if (c < 24) {
                float d = fabsf(ld[e] - tv[e]);
                v_box += (d < 1.f) ? 0.5f * d * d : d - 0.5f;
            } else if (c == 24) {
                v_obj -= ld[e];          // bce(x,1)=bce0(x)-x
            }
        }
    }
    #pragma unroll
    for (int o = 16; o > 0; o >>= 1) {
        v_cls += __shfl_down(v_cls, o, 32);
        v_box += __shfl_down(v_box, o, 32);
    }
    float s_obj = __shfl(v_obj, 24, 32);
    if (c == 0)
        shG[g] = make_float4(s_obj, v_np, v_cls, v_box);
    __syncthreads();
    if (t == 0) {
        float4 r = make_float4(0.f, 0.f, 0.f, 0.f);
        #pragma unroll
        for (int k = 0; k < 8; ++k) {
            r.x += shG[k].x; r.y += shG[k].y; r.z += shG[k].z; r.w += shG[k].w;
        }
        Gout[gi] = r;
    }
}

__global__ void final_combine(const float* __restrict__ Aout, const float4* __restrict__ Gout,
                              float* __restrict__ out) {
    int t = threadIdx.x;
    // A sums per level
    float a0 = 0, a1 = 0, a2 = 0;
    for (int e = t; e < NA0; e += TPB)             a0 += Aout[e];
    for (int e = NA0 + t; e < NA0 + NA1; e += TPB) a1 += Aout[e];
    for (int e = NA0 + NA1 + t; e < NA; e += TPB)  a2 += Aout[e];
    // G sums per level (128 float4 each)
    float o0 = 0, n0 = 0, c0 = 0, b0 = 0;
    float o1 = 0, n1 = 0, c1 = 0, b1 = 0;
    float o2 = 0, n2 = 0, c2 = 0, b2 = 0;
    for (int e = t; e < NG_PER_LVL; e += TPB) {
        float4 v = Gout[e];                  o0 += v.x; n0 += v.y; c0 += v.z; b0 += v.w;
    }
    for (int e = t; e < NG_PER_LVL; e += TPB) {
        float4 v = Gout[NG_PER_LVL + e];     o1 += v.x; n1 += v.y; c1 += v.z; b1 += v.w;
    }
    for (int e = t; e < NG_PER_LVL; e += TPB) {
        float4 v = Gout[2 * NG_PER_LVL + e]; o2 += v.x; n2 += v.y; c2 += v.z; b2 += v.w;
    }
    a0 = wave_sum(a0); a1 = wave_sum(a1); a2 = wave_sum(a2);
    o0 = wave_sum(o0); n0 = wave_sum(n0); c0 = wave_sum(c0); b0 = wave_sum(b0);
    o1 = wave_sum(o1); n1 = wave_sum(n1); c1 = wave_sum(c1); b1 = wave_sum(b1);
    o2 = wave_sum(o2); n2 = wave_sum(n2); c2 = wave_sum(c2); b2 = wave_sum(b2);
    __shared__ float s[4][15];
    int wid = t >> 6, lane = t & 63;
    if (lane == 0) {
        s[wid][0] = a0; s[wid][1] = a1; s[wid][2] = a2;
        s[wid][3]  = o0; s[wid][4]  = n0; s[wid][5]  = c0; s[wid][6]  = b0;
        s[wid][7]  = o1; s[wid][8]  = n1; s[wid][9]  = c1; s[wid][10] = b1;
        s[wid][11] = o2; s[wid][12] = n2; s[wid][13] = c2; s[wid][14] = b2;
    }
    __syncthreads();
    if (t == 0) {
        float r[15];
        #pragma unroll
        for (int k = 0; k < 15; ++k)
            r[k] = s[0][k] + s[1][k] + s[2][k] + s[3][k];
        float np0 = fmaxf(r[4],  1.f);
        float np1 = fmaxf(r[8],  1.f);
        float np2 = fmaxf(r[12], 1.f);
        float lo = (r[0] + r[3])  / (float)C0
                 + (r[1] + r[7])  / (float)C1
                 + (r[2] + r[11]) / (float)C2;
        float lc = r[5] / np0 + r[9]  / np1 + r[13] / np2;
        float lb = r[6] / np0 + r[10] / np1 + r[14] / np2;
        out[0] = lc + lb + lo;
        out[1] = lc;
        out[2] = lb;
        out[3] = lo;
    }
}

extern "C" void kernel_launch(void* const* d_in, const int* in_sizes, int n_in,
                              void* d_out, int out_size, void* d_ws, size_t ws_size,
                              hipStream_t stream) {
    AllPtrs p;
    p.cls0 = (const float*)d_in[0]; p.box0 = (const float*)d_in[1]; p.obj0 = (const float*)d_in[2];
    p.cls1 = (const float*)d_in[3]; p.box1 = (const float*)d_in[4]; p.obj1 = (const float*)d_in[5];
    p.cls2 = (const float*)d_in[6]; p.box2 = (const float*)d_in[7]; p.obj2 = (const float*)d_in[8];
    const float4* boxes  = (const float4*)d_in[9];
    const int*    labels = (const int*)d_in[10];
    float* out = (float*)d_out;

    // workspace: Gout float4[384] at 0 (6144 B), Aout float[1050] after
    char* ws = (char*)d_ws;
    float4* Gout = (float4*)ws;
    float*  Aout = (float*)(ws + NG * sizeof(float4));

    fused_loss<<<NBLK, TPB, 0, stream>>>(p, boxes, labels, Aout, Gout);
    final_combine<<<1, TPB, 0, stream>>>(Aout, Gout, out);
}